// Round 6
// baseline (410.766 us; speedup 1.0000x reference)
//
#include <hip/hip_runtime.h>
#include <hip/hip_bf16.h>
#include <hip/hip_cooperative_groups.h>
#include <math.h>

namespace cg = cooperative_groups;

typedef __hip_bfloat16 bf16;
typedef _Float16 f16;
typedef f16  f16x8  __attribute__((ext_vector_type(8)));
typedef short short8 __attribute__((ext_vector_type(8)));
typedef unsigned short ushort8 __attribute__((ext_vector_type(8)));
typedef float floatx4 __attribute__((ext_vector_type(4)));

#define L_SEQ 4096
#define BATCH 2
#define DIM   96
#define DI    192
#define DS    16
#define HID   192
#define NPOS  (BATCH * L_SEQ)   // 8192
#define NCH   256               // chunks per sequence
#define CHUNK 16                // L_SEQ / NCH
#define GRP   16                // chunks per group (one block)
#define NGRP  (NCH / GRP)       // 16 groups
#define LDBL  40                // padded x_dbl row stride: dt[0:6), B[8:24), C[24:40)
#define LOG2E 1.44269504088896f
#define TP    32                // positions per LN block

__device__ __forceinline__ float silu_f(float x) { return x / (1.f + __expf(-x)); }
__device__ __forceinline__ float softplus_f(float x) {
    return fmaxf(x, 0.f) + __logf(1.f + __expf(-fabsf(x)));
}
__device__ __forceinline__ float b2f(bf16 v) { return __bfloat162float(v); }
__device__ __forceinline__ float us2f(unsigned short u) {
    union { unsigned int i; float f; } cv; cv.i = ((unsigned int)u) << 16; return cv.f;
}

// ---------------------------------------------------------------------------
// K1: LDS-tiled double layernorm -> XNbf (channel-last bf16).
// Prep (weight cast / A2 table / dw transpose) fused as extra blocks.
// ---------------------------------------------------------------------------
__global__ void k_ln12_prep(const float* __restrict__ x,
                            const float* __restrict__ ln1w, const float* __restrict__ ln1b,
                            const float* __restrict__ mnw,  const float* __restrict__ mnb,
                            bf16* __restrict__ XNbf,
                            const float* __restrict__ fWin, const float* __restrict__ bWin,
                            const float* __restrict__ fWx,  const float* __restrict__ bWx,
                            const float* __restrict__ Wout, const float* __restrict__ mwin,
                            const float* __restrict__ mwout,
                            const float* __restrict__ fAlog, const float* __restrict__ bAlog,
                            const float* __restrict__ mdw1, const float* __restrict__ mdw2,
                            const float* __restrict__ mdw3,
                            bf16* __restrict__ war, float* __restrict__ a2tab,
                            float* __restrict__ mdwt) {
    __shared__ float xt[DIM][TP + 1];
    __shared__ float rs[8][TP], rss[8][TP];
    __shared__ float uu[TP], rr[TP];
    if (blockIdx.x >= NPOS / TP) {
        // ---- prep path ----
        int i = (blockIdx.x - NPOS / TP) * 256 + threadIdx.x;
        if (i < 180480) {
            float v;
            if (i < 36864)        v = fWin[i];
            else if (i < 73728)   v = bWin[i - 36864];
            else if (i < 81024)   v = fWx[i - 73728];
            else if (i < 88320)   v = bWx[i - 81024];
            else if (i < 106752)  v = Wout[i - 88320];
            else if (i < 162048)  v = mwin[i - 106752];
            else                  v = mwout[i - 162048];
            war[i] = __float2bfloat16(v);
        } else if (i < 186624) {
            int j = i - 180480;                 // 0..6143
            int dirq = j / 3072, rem = j % 3072;
            const float* al = dirq ? bAlog : fAlog;
            a2tab[j] = -__expf(al[rem]) * LOG2E;
        } else if (i < 191808) {
            int j = i - 186624;                 // 0..5183
            int cv = j / 1728, rem = j % 1728;
            int tap = rem / 192, c = rem % 192;
            const float* src = (cv == 0) ? mdw1 : (cv == 1) ? mdw2 : mdw3;
            mdwt[j] = src[c * 9 + tap];
        }
        return;
    }
    // ---- LN path ----
    int p0 = blockIdx.x * TP;
    int b = p0 >> 12, l0 = p0 & (L_SEQ - 1);
    int t = threadIdx.x;
    int tg = t >> 5, li = t & 31;

    for (int idx = t; idx < DIM * TP; idx += 256) {
        int c = idx >> 5, q = idx & 31;
        xt[c][q] = x[((size_t)(b * DIM + c)) * L_SEQ + l0 + q];
    }
    __syncthreads();
    {
        float s = 0.f, ss = 0.f;
        for (int c = tg; c < DIM; c += 8) { float v = xt[c][li]; s += v; ss += v * v; }
        rs[tg][li] = s; rss[tg][li] = ss;
    }
    __syncthreads();
    if (t < TP) {
        float s = 0.f, ss = 0.f;
#pragma unroll
        for (int g = 0; g < 8; g++) { s += rs[g][t]; ss += rss[g][t]; }
        float u = s / DIM;
        uu[t] = u; rr[t] = rsqrtf(ss / DIM - u * u + 1e-6f);
    }
    __syncthreads();
    {
        float u = uu[li], r = rr[li];
        float s2 = 0.f, ss2 = 0.f;
        for (int c = tg; c < DIM; c += 8) {
            float tv = ln1w[c] * (xt[c][li] - u) * r + ln1b[c];
            xt[c][li] = tv;
            s2 += tv; ss2 += tv * tv;
        }
        rs[tg][li] = s2; rss[tg][li] = ss2;
    }
    __syncthreads();
    if (t < TP) {
        float s = 0.f, ss = 0.f;
#pragma unroll
        for (int g = 0; g < 8; g++) { s += rs[g][t]; ss += rss[g][t]; }
        float u = s / DIM;
        uu[t] = u; rr[t] = rsqrtf(ss / DIM - u * u + 1e-5f);
    }
    __syncthreads();
    for (int idx = t; idx < DIM * TP; idx += 256) {
        int q = idx / DIM, c = idx % DIM;
        XNbf[(size_t)(p0 + q) * DIM + c] =
            __float2bfloat16((xt[c][q] - uu[q]) * rr[q] * mnw[c] + mnb[c]);
    }
}

// ---------------------------------------------------------------------------
// K2: MFMA NT GEMM, 2-dir batched via blockIdx.z (in-projection).
// ---------------------------------------------------------------------------
__global__ void mfma_nt_dir(const bf16* __restrict__ A0, const bf16* __restrict__ A1,
                            const bf16* __restrict__ W0, const bf16* __restrict__ W1,
                            void* __restrict__ C0, void* __restrict__ C1,
                            int M, int N, int K, int ldc, int pad6, int obf) {
    int z = blockIdx.z;
    const bf16* A = z ? A1 : A0;
    const bf16* W = z ? W1 : W0;
    void* C = z ? C1 : C0;
    int wave = threadIdx.x >> 6, lane = threadIdx.x & 63;
    int m0 = blockIdx.x * 64 + wave * 16;
    int n0 = blockIdx.y * 64;
    int lm = lane & 15, quad = lane >> 4;
    const short* Ap = (const short*)A + (size_t)(m0 + lm) * K + quad * 8;
    const short* Wp = (const short*)W;
    floatx4 acc[4];
#pragma unroll
    for (int t = 0; t < 4; t++) acc[t] = (floatx4){0.f, 0.f, 0.f, 0.f};
    for (int k0 = 0; k0 < K; k0 += 32) {
        short8 a = *(const short8*)(Ap + k0);
#pragma unroll
        for (int t = 0; t < 4; t++) {
            int n = n0 + t * 16 + lm;
            short8 b = (n < N) ? *(const short8*)(Wp + (size_t)n * K + k0 + quad * 8)
                               : (short8){0,0,0,0,0,0,0,0};
            acc[t] = __builtin_amdgcn_mfma_f32_16x16x32_bf16(a, b, acc[t], 0, 0, 0);
        }
    }
#pragma unroll
    for (int t = 0; t < 4; t++) {
        int n = n0 + t * 16 + lm;
        if (n < N) {
            int nn = (pad6 && n >= 6) ? n + 2 : n;
#pragma unroll
            for (int r = 0; r < 4; r++) {
                int m = m0 + quad * 4 + r;
                if (obf) ((bf16*)C)[(size_t)m * ldc + nn] = __float2bfloat16(acc[t][r]);
                else     ((float*)C)[(size_t)m * ldc + nn] = acc[t][r];
            }
        }
    }
}

// ---------------------------------------------------------------------------
// K3: dwconv1d k=4 + bias + silu fused with x_dbl projection GEMM.
// Block = 64 positions, one dir (blockIdx.y). XS kept in LDS for the GEMM.
// ---------------------------------------------------------------------------
__global__ void k_conv_dbl(const bf16* __restrict__ XZF, const bf16* __restrict__ XZB,
                           const float* __restrict__ fw, const float* __restrict__ fb,
                           const float* __restrict__ bw, const float* __restrict__ bb,
                           const bf16* __restrict__ fWxB, const bf16* __restrict__ bWxB,
                           float* __restrict__ DBLF, float* __restrict__ DBLB,
                           bf16* __restrict__ XSF, bf16* __restrict__ XSB) {
    __shared__ __align__(16) unsigned short xs_t[64][200];
    int dirb = blockIdx.y;
    int p0 = blockIdx.x * 64;
    const bf16* XZ = dirb ? XZB : XZF;
    const float* cw = dirb ? bw : fw;
    const float* cb = dirb ? bb : fb;
    bf16* XS = dirb ? XSB : XSF;

    for (int u = threadIdx.x; u < 64 * 24; u += 256) {
        int dg = u % 24, pl = u / 24;
        int p = p0 + pl;
        int b = p >> 12, l = p & (L_SEQ - 1);
        int d0 = dg * 8;
        float4 w[8];
#pragma unroll
        for (int j = 0; j < 8; j++) w[j] = *(const float4*)(cw + (d0 + j) * 4);
        float acc[8];
#pragma unroll
        for (int j = 0; j < 8; j++) acc[j] = cb[d0 + j];
#pragma unroll
        for (int k = 0; k < 4; k++) {
            int ls = dirb ? (l + 3 - k) : (l - 3 + k);
            if (ls >= 0 && ls < L_SEQ) {
                ushort8 xv = *(const ushort8*)((const unsigned short*)XZ +
                               ((size_t)(b * L_SEQ + ls)) * 384 + d0);
#pragma unroll
                for (int j = 0; j < 8; j++) {
                    float wk = (k == 0) ? w[j].x : (k == 1) ? w[j].y : (k == 2) ? w[j].z : w[j].w;
                    acc[j] += wk * us2f(xv[j]);
                }
            }
        }
        ushort8 ov;
#pragma unroll
        for (int j = 0; j < 8; j++) {
            bf16 tv = __float2bfloat16(silu_f(acc[j]));
            ov[j] = *(unsigned short*)&tv;
        }
        *(ushort8*)((unsigned short*)XS + (size_t)p * DI + d0) = ov;
        *(ushort8*)&xs_t[pl][d0] = ov;
    }
    __syncthreads();
    // ---- x_dbl GEMM: DBL[p0..p0+63][38 cols -> padded 40] ----
    int t = threadIdx.x;
    int w = t >> 6, lane = t & 63;
    int lm = lane & 15, quad = lane >> 4;
    const bf16* Wx = dirb ? bWxB : fWxB;
    float* DBL = dirb ? DBLB : DBLF;
    floatx4 acc[3];
#pragma unroll
    for (int tt = 0; tt < 3; tt++) acc[tt] = (floatx4){0.f, 0.f, 0.f, 0.f};
    const unsigned short* ar = &xs_t[w * 16 + lm][0];
#pragma unroll
    for (int k = 0; k < 6; k++) {
        int k0 = k * 32 + quad * 8;
        short8 a = *(const short8*)(ar + k0);
#pragma unroll
        for (int tt = 0; tt < 3; tt++) {
            int n = tt * 16 + lm;
            short8 bq = (n < 38) ? *(const short8*)((const short*)Wx + n * 192 + k0)
                                 : (short8){0,0,0,0,0,0,0,0};
            acc[tt] = __builtin_amdgcn_mfma_f32_16x16x32_bf16(a, bq, acc[tt], 0, 0, 0);
        }
    }
#pragma unroll
    for (int tt = 0; tt < 3; tt++) {
        int n = tt * 16 + lm;
        if (n < 38) {
            int nn = (n >= 6) ? n + 2 : n;
#pragma unroll
            for (int r = 0; r < 4; r++) {
                int m = p0 + w * 16 + quad * 4 + r;
                DBL[(size_t)m * LDBL + nn] = acc[tt][r];
            }
        }
    }
}

// ---------------------------------------------------------------------------
// K4: fused chunked parallel scan (cooperative, grid-wide sync).
// Block = (16 chunks x 16 d); grid = (12 dslices, 16 grps, 4 dirb) = 768.
// phase1: chunk scan -> LDS;  phase2: intra-group exclusive compose in LDS,
// group totals -> global Pg/Qg;  grid.sync;  phaseA: cross-group prefix;
// phase3: replay from LDS exclusives (no global P/Q round-trip).
// ---------------------------------------------------------------------------
__global__ void __launch_bounds__(256, 3)
k_scan_fused(const float* __restrict__ DBLF, const float* __restrict__ DBLB,
             const bf16* __restrict__ XSF,  const bf16* __restrict__ XSB,
             const bf16* __restrict__ XZF,  const bf16* __restrict__ XZB,
             const float* __restrict__ fWdt, const float* __restrict__ fbdt,
             const float* __restrict__ bWdt, const float* __restrict__ bbdt,
             const float* __restrict__ a2tab,
             const float* __restrict__ fD,    const float* __restrict__ bD,
             float* __restrict__ Pg, float* __restrict__ Qg,
             bf16* __restrict__ YSF, bf16* __restrict__ YSB) {
    __shared__ f16x8 Pl[2][GRP][16];   // [s8][chunk][dl]
    __shared__ f16x8 Ql[2][GRP][16];
    __shared__ float qx[16][17];       // [dl][s] group-exclusive prefix
    int dsl = blockIdx.x, grp = blockIdx.y, dirb = blockIdx.z;
    int t = threadIdx.x;
    int chunk = t >> 4, dl = t & 15;
    int d = dsl * 16 + dl;
    int b = dirb & 1, dir = dirb >> 1;
    int gc = grp * GRP + chunk;

    const float* DBL = dir ? DBLB : DBLF;
    const bf16*  XS  = dir ? XSB  : XSF;
    const bf16*  XZ  = dir ? XZB  : XZF;
    const float* wdt = (dir ? bWdt : fWdt) + d * 6;
    float bdtv = (dir ? bbdt : fbdt)[d];
    float Dp = dir ? bD[d] : fD[d];
    bf16* Y = dir ? YSB : YSF;

    float wd[6];
#pragma unroll
    for (int r = 0; r < 6; r++) wd[r] = wdt[r];
    const float* a2p = a2tab + (dir * DI + d) * 16;
    float A2[16], h[16];
#pragma unroll
    for (int v = 0; v < 4; v++) {
        float4 a2v = *(const float4*)(a2p + 4 * v);
        A2[4*v] = a2v.x; A2[4*v+1] = a2v.y; A2[4*v+2] = a2v.z; A2[4*v+3] = a2v.w;
    }
#pragma unroll
    for (int s = 0; s < 16; s++) h[s] = 0.f;

    int l0 = dir ? (L_SEQ - 1 - gc * CHUNK) : gc * CHUNK;
    int stp = dir ? -1 : 1;
    float sumdel = 0.f;

    // ---- phase 1: chunk scan ----
    {
        int l = l0;
        for (int i = 0; i < CHUNK; i++) {
            size_t p = (size_t)b * L_SEQ + l;
            const float* row = DBL + p * LDBL;
            float dtv = bdtv;
#pragma unroll
            for (int r = 0; r < 6; r++) dtv += row[r] * wd[r];
            float del = softplus_f(dtv);
            float xs  = b2f(XS[p * DI + d]);
            const float4* bm = (const float4*)(row + 8);
            float4 B0 = bm[0], B1 = bm[1], B2 = bm[2], B3 = bm[3];
            float Bm[16] = {B0.x,B0.y,B0.z,B0.w, B1.x,B1.y,B1.z,B1.w,
                            B2.x,B2.y,B2.z,B2.w, B3.x,B3.y,B3.z,B3.w};
            float dx = del * xs;
            sumdel += del;
#pragma unroll
            for (int s = 0; s < 16; s++) {
                float dA = exp2f(del * A2[s]);
                h[s] = dA * h[s] + dx * Bm[s];
            }
            l += stp;
        }
        f16x8 p0, p1, q0, q1;
#pragma unroll
        for (int j = 0; j < 8; j++) {
            q0[j] = (f16)h[j];
            q1[j] = (f16)h[8 + j];
            p0[j] = (f16)exp2f(A2[j] * sumdel);
            p1[j] = (f16)exp2f(A2[8 + j] * sumdel);
        }
        Pl[0][chunk][dl] = p0; Pl[1][chunk][dl] = p1;
        Ql[0][chunk][dl] = q0; Ql[1][chunk][dl] = q1;
    }
    __syncthreads();

    // ---- phase 2: exclusive compose over GRP chunks, one (d,s) per thread ----
    {
        int s  = t & 15, dl2 = t >> 4;
        int s8 = s >> 3, sl = s & 7;
        f16* Pp = (f16*)&Pl[s8][0][dl2];   // chunk stride = 16 f16x8 = 128 f16
        f16* Qp = (f16*)&Ql[s8][0][dl2];
        float runP = 1.f, runQ = 0.f;
#pragma unroll
        for (int c = 0; c < GRP; c++) {
            float pv = (float)Pp[c * 128 + sl];
            float qv = (float)Qp[c * 128 + sl];
            Pp[c * 128 + sl] = (f16)runP;
            Qp[c * 128 + sl] = (f16)runQ;
            runQ = pv * runQ + qv;
            runP *= pv;
        }
        int d2 = dsl * 16 + dl2;
        size_t gidx = (((size_t)(dirb * NGRP + grp)) * DI + d2) * 16 + s;
        Pg[gidx] = runP;
        Qg[gidx] = runQ;
    }
    __threadfence();
    cg::this_grid().sync();

    // ---- phase A: cross-group exclusive prefix from (Pg,Qg) ----
    {
        int dl2 = t >> 4, s = t & 15;
        int d2 = dsl * 16 + dl2;
        float runQ = 0.f;
        for (int g = 0; g < grp; g++) {
            size_t i = (((size_t)(dirb * NGRP + g)) * DI + d2) * 16 + s;
            runQ = Pg[i] * runQ + Qg[i];
        }
        qx[dl2][s] = runQ;
    }
    __syncthreads();

    // ---- phase 3: replay; h_start = Pexc * qx + Qexc (all from LDS) ----
    {
        f16x8 pe0 = Pl[0][chunk][dl];
        f16x8 pe1 = Pl[1][chunk][dl];
        f16x8 qe0 = Ql[0][chunk][dl];
        f16x8 qe1 = Ql[1][chunk][dl];
#pragma unroll
        for (int j = 0; j < 8; j++) {
            h[j]     = (float)pe0[j] * qx[dl][j]     + (float)qe0[j];
            h[8 + j] = (float)pe1[j] * qx[dl][8 + j] + (float)qe1[j];
        }
    }
    {
        int l = l0;
        for (int i = 0; i < CHUNK; i++) {
            size_t p = (size_t)b * L_SEQ + l;
            const float* row = DBL + p * LDBL;
            float dtv = bdtv;
#pragma unroll
            for (int r = 0; r < 6; r++) dtv += row[r] * wd[r];
            float del = softplus_f(dtv);
            float xs  = b2f(XS[p * DI + d]);
            float z   = b2f(XZ[p * 384 + 192 + d]);
            const float4* bm = (const float4*)(row + 8);
            float4 B0 = bm[0], B1 = bm[1], B2 = bm[2], B3 = bm[3];
            float4 C0 = bm[4], C1 = bm[5], C2 = bm[6], C3 = bm[7];
            float Bm[16] = {B0.x,B0.y,B0.z,B0.w, B1.x,B1.y,B1.z,B1.w,
                            B2.x,B2.y,B2.z,B2.w, B3.x,B3.y,B3.z,B3.w};
            float Cm[16] = {C0.x,C0.y,C0.z,C0.w, C1.x,C1.y,C1.z,C1.w,
                            C2.x,C2.y,C2.z,C2.w, C3.x,C3.y,C3.z,C3.w};
            float dx = del * xs;
            float pr = 0.f;
#pragma unroll
            for (int s = 0; s < 16; s++) {
                float dA = exp2f(del * A2[s]);
                h[s] = dA * h[s] + dx * Bm[s];
                pr += h[s] * Cm[s];
            }
            Y[p * DI + d] = __float2bfloat16((pr + xs * Dp) * silu_f(z));
            l += stp;
        }
    }
}

// ---------------------------------------------------------------------------
// K5: out-projection (dual-A MFMA, YO in LDS) + residual + double LN
// + msff in-projection GEMM fused (XM2 tile stays in LDS; H written direct).
// ---------------------------------------------------------------------------
__global__ void k_out_mid(const bf16* __restrict__ Y1, const bf16* __restrict__ Y2,
                          const bf16* __restrict__ W,
                          const float* __restrict__ x, const float* __restrict__ gamma1,
                          const float* __restrict__ ln1w, const float* __restrict__ ln1b,
                          const bf16* __restrict__ mwinB,
                          float* __restrict__ XMID, bf16* __restrict__ H) {
    __shared__ float yt[DIM][TP + 1];
    __shared__ float xt[DIM][TP + 1];
    __shared__ float rs[8][TP], rss[8][TP];
    __shared__ float uu[TP], rr[TP];
    __shared__ __align__(16) unsigned short xmt[TP][104];
    int p0 = blockIdx.x * TP;
    int b = p0 >> 12, l0 = p0 & (L_SEQ - 1);
    int t = threadIdx.x;
    int tg = t >> 5, li = t & 31;

    // GEMM-1: YO tile = (Y1+Y2)[p0..p0+31] @ Wout^T -> yt[c][pos]
    {
        int w = t >> 6, lane = t & 63;
        int lm = lane & 15, quad = lane >> 4;
        int mh = w & 1, nb = (w >> 1) * 3;
        const short* A1p = (const short*)Y1 + (size_t)(p0 + mh * 16 + lm) * 192 + quad * 8;
        const short* A2p = (const short*)Y2 + (size_t)(p0 + mh * 16 + lm) * 192 + quad * 8;
        const short* Wp  = (const short*)W;
        floatx4 acc[3];
#pragma unroll
        for (int tt = 0; tt < 3; tt++) acc[tt] = (floatx4){0.f, 0.f, 0.f, 0.f};
#pragma unroll
        for (int k = 0; k < 6; k++) {
            int k0 = k * 32;
            short8 a1 = *(const short8*)(A1p + k0);
            short8 a2 = *(const short8*)(A2p + k0);
#pragma unroll
            for (int tt = 0; tt < 3; tt++) {
                int n = (nb + tt) * 16 + lm;
                short8 bq = *(const short8*)(Wp + (size_t)n * 192 + k0 + quad * 8);
                acc[tt] = __builtin_amdgcn_mfma_f32_16x16x32_bf16(a1, bq, acc[tt], 0, 0, 0);
                acc[tt] = __builtin_amdgcn_mfma_f32_16x16x32_bf16(a2, bq, acc[tt], 0, 0, 0);
            }
        }
#pragma unroll
        for (int tt = 0; tt < 3; tt++) {
            int c = (nb + tt) * 16 + lm;
#pragma unroll
            for (int r = 0; r < 4; r++)
                yt[c][mh * 16 + quad * 4 + r] = acc[tt][r];
        }
    }
    for (int idx = t; idx < DIM * TP; idx += 256) {
        int c = idx >> 5, q = idx & 31;
        xt[c][q] = x[((size_t)(b * DIM + c)) * L_SEQ + l0 + q];
    }
    __syncthreads();
    // stats of x (LN1)
    {
        float s = 0.f, ss = 0.f;
        for (int c = tg; c < DIM; c += 8) { float v = xt[c][li]; s += v; ss += v * v; }
        rs[tg][li] = s; rss[tg][li] = ss;
    }
    __syncthreads();
    if (t < TP) {
        float s = 0.f, ss = 0.f;
#pragma unroll
        for (int g = 0; g < 8; g++) { s += rs[g][t]; ss += rss[g][t]; }
        float u = s / DIM;
        uu[t] = u; rr[t] = rsqrtf(ss / DIM - u * u + 1e-6f);
    }
    __syncthreads();
    // v = x + gamma1*(yo + ln1(x)); stats of v
    {
        float u = uu[li], r = rr[li];
        float s = 0.f, ss = 0.f;
        for (int c = tg; c < DIM; c += 8) {
            float xv = xt[c][li];
            float x1 = ln1w[c] * (xv - u) * r + ln1b[c];
            float v = xv + gamma1[c] * (yt[c][li] + x1);
            XMID[((size_t)(b * DIM + c)) * L_SEQ + l0 + li] = v;
            xt[c][li] = v;
            s += v; ss += v * v;
        }
        rs[tg][li] = s; rss[tg][li] = ss;
    }
    __syncthreads();
    if (t < TP) {
        float s = 0.f, ss = 0.f;
#pragma unroll
        for (int g = 0; g < 8; g++) { s += rs[g][t]; ss += rss[g][t]; }
        float u = s / DIM;
        uu[t] = u; rr[t] = rsqrtf(ss / DIM - u * u + 1e-6f);
    }
    __syncthreads();
    // XM2 tile -> LDS (bf16, stride 104 shorts: 16B-aligned rows, 2-way bank = free)
    for (int idx = t; idx < DIM * TP; idx += 256) {
        int q = idx / DIM, c = idx % DIM;
        bf16 tv = __float2bfloat16(ln1w[c] * (xt[c][q] - uu[q]) * rr[q] + ln1b[c]);
        xmt[q][c] = *(unsigned short*)&tv;
    }
    __syncthreads();
    // GEMM-2: H[p0..p0+31][0..575] = XM2 @ mwin^T (K=96), acc reused per tile
    {
        int w = t >> 6, lane = t & 63;
        int lm = lane & 15, quad = lane >> 4;
        int mh = w & 1, ng = w >> 1;   // ng 0..1 -> n-tile halves
        const unsigned short* ar = &xmt[mh * 16 + lm][0];
        short8 a[3];
#pragma unroll
        for (int k = 0; k < 3; k++)
            a[k] = *(const short8*)(ar + k * 32 + quad * 8);
        const short* Wp = (const short*)mwinB;
#pragma unroll
        for (int tt = 0; tt < 18; tt++) {
            int n = (ng * 18 + tt) * 16 + lm;
            floatx4 acc = (floatx4){0.f, 0.f, 0.f, 0.f};
#pragma unroll
            for (int k = 0; k < 3; k++) {
                short8 bq = *(const short8*)(Wp + (size_t)n * 96 + k * 32 + quad * 8);
                acc = __builtin_amdgcn_mfma_f32_16x16x32_bf16(a[k], bq, acc, 0, 0, 0);
            }
#pragma unroll
            for (int r = 0; r < 4; r++) {
                int m = p0 + mh * 16 + quad * 4 + r;
                H[(size_t)m * 576 + n] = __float2bfloat16(acc[r]);
            }
        }
    }
}

// ---------------------------------------------------------------------------
// K6: fused dilated dwconvs + GELU gate (G in LDS) + msff out-projection
// + final residual (planar f32 out). Block = 32 positions.
// ---------------------------------------------------------------------------
__global__ void k_msff_outres(const bf16* __restrict__ H, const float* __restrict__ mdwt,
                              const bf16* __restrict__ mwoutB,
                              const float* __restrict__ XMID, const float* __restrict__ gamma2,
                              float* __restrict__ out) {
    __shared__ __align__(16) unsigned short gt[32][200];
    int p0 = blockIdx.x * 32;
    int t = threadIdx.x;
    const unsigned short* Hu = (const unsigned short*)H;

    for (int u = t; u < 32 * 24; u += 256) {
        int cg = u % 24, pl = u / 24;
        int p = p0 + pl;
        int c0 = cg * 8;
        int b = p >> 12, l = p & (L_SEQ - 1);
        int y = l >> 6, xc = l & 63;
        float a1[8] = {}, a2[8] = {}, a3[8] = {};
#pragma unroll
        for (int ky = 0; ky < 3; ky++) {
#pragma unroll
            for (int kx = 0; kx < 3; kx++) {
                int tap = ky * 3 + kx;
                {
                    int y1 = y + (ky - 1), x1 = xc + (kx - 1);
                    if (y1 >= 0 && y1 < 64 && x1 >= 0 && x1 < 64) {
                        float4 w0 = *(const float4*)(mdwt + tap * 192 + c0);
                        float4 w1 = *(const float4*)(mdwt + tap * 192 + c0 + 4);
                        ushort8 hv = *(const ushort8*)(Hu +
                            ((size_t)(b * L_SEQ + y1 * 64 + x1)) * 576 + c0);
                        float wv[8] = {w0.x,w0.y,w0.z,w0.w, w1.x,w1.y,w1.z,w1.w};
#pragma unroll
                        for (int j = 0; j < 8; j++) a1[j] += wv[j] * us2f(hv[j]);
                    }
                }
                {
                    int y2 = y + (ky - 1) * 2, x2 = xc + (kx - 1) * 2;
                    if (y2 >= 0 && y2 < 64 && x2 >= 0 && x2 < 64) {
                        float4 w0 = *(const float4*)(mdwt + (9 + tap) * 192 + c0);
                        float4 w1 = *(const float4*)(mdwt + (9 + tap) * 192 + c0 + 4);
                        ushort8 hv = *(const ushort8*)(Hu +
                            ((size_t)(b * L_SEQ + y2 * 64 + x2)) * 576 + 192 + c0);
                        float wv[8] = {w0.x,w0.y,w0.z,w0.w, w1.x,w1.y,w1.z,w1.w};
#pragma unroll
                        for (int j = 0; j < 8; j++) a2[j] += wv[j] * us2f(hv[j]);
                    }
                }
                {
                    int y3 = y + (ky - 1) * 3, x3 = xc + (kx - 1) * 3;
                    if (y3 >= 0 && y3 < 64 && x3 >= 0 && x3 < 64) {
                        float4 w0 = *(const float4*)(mdwt + (18 + tap) * 192 + c0);
                        float4 w1 = *(const float4*)(mdwt + (18 + tap) * 192 + c0 + 4);
                        ushort8 hv = *(const ushort8*)(Hu +
                            ((size_t)(b * L_SEQ + y3 * 64 + x3)) * 576 + 384 + c0);
                        float wv[8] = {w0.x,w0.y,w0.z,w0.w, w1.x,w1.y,w1.z,w1.w};
#pragma unroll
                        for (int j = 0; j < 8; j++) a3[j] += wv[j] * us2f(hv[j]);
                    }
                }
            }
        }
        ushort8 ov;
#pragma unroll
        for (int j = 0; j < 8; j++) {
            float ge = 0.5f * a1[j] * (1.f + erff(a1[j] * 0.70710678118f));
            bf16 tv = __float2bfloat16(ge * a2[j] * a3[j]);
            ov[j] = *(unsigned short*)&tv;
        }
        *(ushort8*)&gt[pl][c0] = ov;
    }
    __syncthreads();
    // GEMM: out = XMID + gamma2 * (mwout @ G^T)   (m = channel, n = position)
    int w = t >> 6, lane = t & 63;
    int lm = lane & 15, quad = lane >> 4;
    int nt = w & 1, mb = (w >> 1) * 3;
    floatx4 acc[3];
#pragma unroll
    for (int tt = 0; tt < 3; tt++) acc[tt] = (floatx4){0.f, 0.f, 0.f, 0.f};
    const unsigned short* br = &gt[nt * 16 + lm][0];
#pragma unroll
    for (int k = 0; k < 6; k++) {
        int k0 = k * 32 + quad * 8;
        short8 bq = *(const short8*)(br + k0);
#pragma unroll
        for (int tt = 0; tt < 3; tt++) {
            int m = (mb + tt) * 16 + lm;
            short8 a = *(const short8*)((const short*)mwoutB + m * 192 + k0);
            acc[tt] = __builtin_amdgcn_mfma_f32_16x16x32_bf16(a, bq, acc[tt], 0, 0, 0);
        }
    }
    int b = p0 >> 12, l0 = p0 & (L_SEQ - 1);
#pragma unroll
    for (int tt = 0; tt < 3; tt++) {
#pragma unroll
        for (int r = 0; r < 4; r++) {
            int m = (mb + tt) * 16 + quad * 4 + r;
            size_t idx = ((size_t)(b * DIM + m)) * L_SEQ + l0 + nt * 16 + lm;
            out[idx] = XMID[idx] + gamma2[m] * acc[tt][r];
        }
    }
}

// ---------------------------------------------------------------------------
extern "C" void kernel_launch(void* const* d_in, const int* in_sizes, int n_in,
                              void* d_out, int out_size, void* d_ws, size_t ws_size,
                              hipStream_t stream) {
    const float* x      = (const float*)d_in[0];
    const float* gamma1 = (const float*)d_in[1];
    const float* gamma2 = (const float*)d_in[2];
    const float* ln1w   = (const float*)d_in[3];
    const float* ln1b   = (const float*)d_in[4];
    const float* mnw    = (const float*)d_in[5];
    const float* mnb    = (const float*)d_in[6];
    const float* fWin   = (const float*)d_in[7];
    const float* fconvw = (const float*)d_in[8];
    const float* fconvb = (const float*)d_in[9];
    const float* fWx    = (const float*)d_in[10];
    const float* fWdt   = (const float*)d_in[11];
    const float* fbdt   = (const float*)d_in[12];
    const float* fAlog  = (const float*)d_in[13];
    const float* fD     = (const float*)d_in[14];
    const float* bWin   = (const float*)d_in[15];
    const float* bconvw = (const float*)d_in[16];
    const float* bconvb = (const float*)d_in[17];
    const float* bWx    = (const float*)d_in[18];
    const float* bWdt   = (const float*)d_in[19];
    const float* bbdt   = (const float*)d_in[20];
    const float* bAlog  = (const float*)d_in[21];
    const float* bD     = (const float*)d_in[22];
    const float* Wout   = (const float*)d_in[23];
    const float* mwin   = (const float*)d_in[24];
    const float* mdw1   = (const float*)d_in[25];
    const float* mdw2   = (const float*)d_in[26];
    const float* mdw3   = (const float*)d_in[27];
    const float* mwout  = (const float*)d_in[28];
    float* out = (float*)d_out;

    float* ws = (float*)d_ws;
    // float offsets
    bf16*  XNbf  = (bf16*)(ws);              // 786432 bf16
    bf16*  XZF   = (bf16*)(ws + 393216);     // 3145728 bf16
    bf16*  XZB   = (bf16*)(ws + 1966080);    // 3145728 bf16
    bf16*  XSF   = (bf16*)(ws + 3538944);    // 1572864 bf16
    bf16*  XSB   = (bf16*)(ws + 4325376);    // 1572864 bf16
    float* DBLF  = ws + 5111808;             // 327680
    float* DBLB  = ws + 5439488;             // 327680
    bf16*  YSFbf = (bf16*)(ws + 12058624);   // 1572864 bf16
    bf16*  YSBbf = (bf16*)(ws + 12845056);   // 1572864 bf16
    float* XMID  = ws + 14417920;            // 786432
    bf16*  Hcl   = (bf16*)(ws + 15597568);   // 4718592 bf16
    bf16*  WAR   = (bf16*)(ws + 18743296);   // 180480 bf16
    float* A2tab = ws + 18833536;            // 6144
    float* MDWT  = ws + 18839680;            // 5184
    float* Pgb   = ws + 18844864;            // 196608 (4*NGRP*DI*16)
    float* Qgb   = ws + 19041472;            // 196608

    const bf16* fWinB  = WAR;
    const bf16* bWinB  = WAR + 36864;
    const bf16* fWxB   = WAR + 73728;
    const bf16* bWxB   = WAR + 81024;
    const bf16* WoutB  = WAR + 88320;
    const bf16* mwinB  = WAR + 106752;
    const bf16* mwoutB = WAR + 162048;

    // 1. double LN (LDS-tiled) + prep as extra blocks
    k_ln12_prep<<<NPOS / TP + 750, 256, 0, stream>>>(
        x, ln1w, ln1b, mnw, mnb, XNbf,
        fWin, bWin, fWx, bWx, Wout, mwin, mwout,
        fAlog, bAlog, mdw1, mdw2, mdw3, WAR, A2tab, MDWT);
    // 2. in-projections, both dirs (clean bf16-weight MFMA)
    mfma_nt_dir<<<dim3(128, 6, 2), 256, 0, stream>>>(XNbf, XNbf, fWinB, bWinB,
                                                     XZF, XZB, NPOS, 384, DIM, 384, 0, 1);
    // 3. dwconv + silu + x_dbl projection (fused, both dirs)
    k_conv_dbl<<<dim3(NPOS / 64, 2), 256, 0, stream>>>(
        XZF, XZB, fconvw, fconvb, bconvw, bconvb,
        fWxB, bWxB, DBLF, DBLB, XSF, XSB);
    // 4. fused chunked parallel scan (cooperative; grid-wide sync inside)
    {
        void* args[] = {
            (void*)&DBLF, (void*)&DBLB, (void*)&XSF, (void*)&XSB,
            (void*)&XZF, (void*)&XZB,
            (void*)&fWdt, (void*)&fbdt, (void*)&bWdt, (void*)&bbdt,
            (void*)&A2tab, (void*)&fD, (void*)&bD,
            (void*)&Pgb, (void*)&Qgb, (void*)&YSFbf, (void*)&YSBbf
        };
        hipLaunchCooperativeKernel((const void*)k_scan_fused,
                                   dim3(DI / 16, NGRP, 4), dim3(256),
                                   args, 0, stream);
    }
    // 5. out-projection + residual + double LN + msff in-projection (fused)
    k_out_mid<<<NPOS / TP, 256, 0, stream>>>(
        YSFbf, YSBbf, WoutB, x, gamma1, ln1w, ln1b, mwinB, XMID, Hcl);
    // 6. msff dwconv/gate + out-projection + final residual (fused) -> out
    k_msff_outres<<<NPOS / 32, 256, 0, stream>>>(Hcl, MDWT, mwoutB, XMID, gamma2, out);
}

// Round 7
// 261.922 us; speedup vs baseline: 1.5683x; 1.5683x over previous
//
#include <hip/hip_runtime.h>
#include <hip/hip_bf16.h>
#include <math.h>

typedef __hip_bfloat16 bf16;
typedef _Float16 f16;
typedef f16  f16x8  __attribute__((ext_vector_type(8)));
typedef short short8 __attribute__((ext_vector_type(8)));
typedef unsigned short ushort8 __attribute__((ext_vector_type(8)));
typedef float floatx4 __attribute__((ext_vector_type(4)));

#define L_SEQ 4096
#define BATCH 2
#define DIM   96
#define DI    192
#define DS    16
#define HID   192
#define NPOS  (BATCH * L_SEQ)   // 8192
#define NCH   256               // chunks per sequence
#define CHUNK 16                // L_SEQ / NCH
#define GRP   16                // chunks per group (one block)
#define NGRP  (NCH / GRP)       // 16 groups
#define LDBL  40                // padded x_dbl row stride: dt[0:6), B[8:24), C[24:40)
#define PLANE (4 * NCH * DI * 8) // 1572864 f16 per s8-plane of Pexc/Qexc
#define LOG2E 1.44269504088896f
#define TP    32                // positions per LN block

__device__ __forceinline__ float silu_f(float x) { return x / (1.f + __expf(-x)); }
__device__ __forceinline__ float softplus_f(float x) {
    return fmaxf(x, 0.f) + __logf(1.f + __expf(-fabsf(x)));
}
__device__ __forceinline__ float b2f(bf16 v) { return __bfloat162float(v); }
__device__ __forceinline__ float us2f(unsigned short u) {
    union { unsigned int i; float f; } cv; cv.i = ((unsigned int)u) << 16; return cv.f;
}

// ---------------------------------------------------------------------------
// K1: LDS-tiled double layernorm -> XNbf (channel-last bf16).
// Prep (weight cast / A2 table / dw transpose) fused as extra blocks.
// ---------------------------------------------------------------------------
__global__ void k_ln12_prep(const float* __restrict__ x,
                            const float* __restrict__ ln1w, const float* __restrict__ ln1b,
                            const float* __restrict__ mnw,  const float* __restrict__ mnb,
                            bf16* __restrict__ XNbf,
                            const float* __restrict__ fWin, const float* __restrict__ bWin,
                            const float* __restrict__ fWx,  const float* __restrict__ bWx,
                            const float* __restrict__ Wout, const float* __restrict__ mwin,
                            const float* __restrict__ mwout,
                            const float* __restrict__ fAlog, const float* __restrict__ bAlog,
                            const float* __restrict__ mdw1, const float* __restrict__ mdw2,
                            const float* __restrict__ mdw3,
                            bf16* __restrict__ war, float* __restrict__ a2tab,
                            float* __restrict__ mdwt) {
    __shared__ float xt[DIM][TP + 1];
    __shared__ float rs[8][TP], rss[8][TP];
    __shared__ float uu[TP], rr[TP];
    if (blockIdx.x >= NPOS / TP) {
        // ---- prep path ----
        int i = (blockIdx.x - NPOS / TP) * 256 + threadIdx.x;
        if (i < 180480) {
            float v;
            if (i < 36864)        v = fWin[i];
            else if (i < 73728)   v = bWin[i - 36864];
            else if (i < 81024)   v = fWx[i - 73728];
            else if (i < 88320)   v = bWx[i - 81024];
            else if (i < 106752)  v = Wout[i - 88320];
            else if (i < 162048)  v = mwin[i - 106752];
            else                  v = mwout[i - 162048];
            war[i] = __float2bfloat16(v);
        } else if (i < 186624) {
            int j = i - 180480;                 // 0..6143
            int dirq = j / 3072, rem = j % 3072;
            const float* al = dirq ? bAlog : fAlog;
            a2tab[j] = -__expf(al[rem]) * LOG2E;
        } else if (i < 191808) {
            int j = i - 186624;                 // 0..5183
            int cv = j / 1728, rem = j % 1728;
            int tap = rem / 192, c = rem % 192;
            const float* src = (cv == 0) ? mdw1 : (cv == 1) ? mdw2 : mdw3;
            mdwt[j] = src[c * 9 + tap];
        }
        return;
    }
    // ---- LN path ----
    int p0 = blockIdx.x * TP;
    int b = p0 >> 12, l0 = p0 & (L_SEQ - 1);
    int t = threadIdx.x;
    int tg = t >> 5, li = t & 31;

    for (int idx = t; idx < DIM * TP; idx += 256) {
        int c = idx >> 5, q = idx & 31;
        xt[c][q] = x[((size_t)(b * DIM + c)) * L_SEQ + l0 + q];
    }
    __syncthreads();
    {
        float s = 0.f, ss = 0.f;
        for (int c = tg; c < DIM; c += 8) { float v = xt[c][li]; s += v; ss += v * v; }
        rs[tg][li] = s; rss[tg][li] = ss;
    }
    __syncthreads();
    if (t < TP) {
        float s = 0.f, ss = 0.f;
#pragma unroll
        for (int g = 0; g < 8; g++) { s += rs[g][t]; ss += rss[g][t]; }
        float u = s / DIM;
        uu[t] = u; rr[t] = rsqrtf(ss / DIM - u * u + 1e-6f);
    }
    __syncthreads();
    {
        float u = uu[li], r = rr[li];
        float s2 = 0.f, ss2 = 0.f;
        for (int c = tg; c < DIM; c += 8) {
            float tv = ln1w[c] * (xt[c][li] - u) * r + ln1b[c];
            xt[c][li] = tv;
            s2 += tv; ss2 += tv * tv;
        }
        rs[tg][li] = s2; rss[tg][li] = ss2;
    }
    __syncthreads();
    if (t < TP) {
        float s = 0.f, ss = 0.f;
#pragma unroll
        for (int g = 0; g < 8; g++) { s += rs[g][t]; ss += rss[g][t]; }
        float u = s / DIM;
        uu[t] = u; rr[t] = rsqrtf(ss / DIM - u * u + 1e-5f);
    }
    __syncthreads();
    for (int idx = t; idx < DIM * TP; idx += 256) {
        int q = idx / DIM, c = idx % DIM;
        XNbf[(size_t)(p0 + q) * DIM + c] =
            __float2bfloat16((xt[c][q] - uu[q]) * rr[q] * mnw[c] + mnb[c]);
    }
}

// ---------------------------------------------------------------------------
// K2: MFMA NT GEMM, 2-dir batched via blockIdx.z (in-projection).
// ---------------------------------------------------------------------------
__global__ void mfma_nt_dir(const bf16* __restrict__ A0, const bf16* __restrict__ A1,
                            const bf16* __restrict__ W0, const bf16* __restrict__ W1,
                            void* __restrict__ C0, void* __restrict__ C1,
                            int M, int N, int K, int ldc, int pad6, int obf) {
    int z = blockIdx.z;
    const bf16* A = z ? A1 : A0;
    const bf16* W = z ? W1 : W0;
    void* C = z ? C1 : C0;
    int wave = threadIdx.x >> 6, lane = threadIdx.x & 63;
    int m0 = blockIdx.x * 64 + wave * 16;
    int n0 = blockIdx.y * 64;
    int lm = lane & 15, quad = lane >> 4;
    const short* Ap = (const short*)A + (size_t)(m0 + lm) * K + quad * 8;
    const short* Wp = (const short*)W;
    floatx4 acc[4];
#pragma unroll
    for (int t = 0; t < 4; t++) acc[t] = (floatx4){0.f, 0.f, 0.f, 0.f};
    for (int k0 = 0; k0 < K; k0 += 32) {
        short8 a = *(const short8*)(Ap + k0);
#pragma unroll
        for (int t = 0; t < 4; t++) {
            int n = n0 + t * 16 + lm;
            short8 b = (n < N) ? *(const short8*)(Wp + (size_t)n * K + k0 + quad * 8)
                               : (short8){0,0,0,0,0,0,0,0};
            acc[t] = __builtin_amdgcn_mfma_f32_16x16x32_bf16(a, b, acc[t], 0, 0, 0);
        }
    }
#pragma unroll
    for (int t = 0; t < 4; t++) {
        int n = n0 + t * 16 + lm;
        if (n < N) {
            int nn = (pad6 && n >= 6) ? n + 2 : n;
#pragma unroll
            for (int r = 0; r < 4; r++) {
                int m = m0 + quad * 4 + r;
                if (obf) ((bf16*)C)[(size_t)m * ldc + nn] = __float2bfloat16(acc[t][r]);
                else     ((float*)C)[(size_t)m * ldc + nn] = acc[t][r];
            }
        }
    }
}

// ---------------------------------------------------------------------------
// K3: dwconv1d k=4 + bias + silu fused with x_dbl projection GEMM.
// Block = 64 positions, one dir (blockIdx.y). XS kept in LDS for the GEMM.
// ---------------------------------------------------------------------------
__global__ void k_conv_dbl(const bf16* __restrict__ XZF, const bf16* __restrict__ XZB,
                           const float* __restrict__ fw, const float* __restrict__ fb,
                           const float* __restrict__ bw, const float* __restrict__ bb,
                           const bf16* __restrict__ fWxB, const bf16* __restrict__ bWxB,
                           float* __restrict__ DBLF, float* __restrict__ DBLB,
                           bf16* __restrict__ XSF, bf16* __restrict__ XSB) {
    __shared__ __align__(16) unsigned short xs_t[64][200];
    int dirb = blockIdx.y;
    int p0 = blockIdx.x * 64;
    const bf16* XZ = dirb ? XZB : XZF;
    const float* cw = dirb ? bw : fw;
    const float* cb = dirb ? bb : fb;
    bf16* XS = dirb ? XSB : XSF;

    for (int u = threadIdx.x; u < 64 * 24; u += 256) {
        int dg = u % 24, pl = u / 24;
        int p = p0 + pl;
        int b = p >> 12, l = p & (L_SEQ - 1);
        int d0 = dg * 8;
        float4 w[8];
#pragma unroll
        for (int j = 0; j < 8; j++) w[j] = *(const float4*)(cw + (d0 + j) * 4);
        float acc[8];
#pragma unroll
        for (int j = 0; j < 8; j++) acc[j] = cb[d0 + j];
#pragma unroll
        for (int k = 0; k < 4; k++) {
            int ls = dirb ? (l + 3 - k) : (l - 3 + k);
            if (ls >= 0 && ls < L_SEQ) {
                ushort8 xv = *(const ushort8*)((const unsigned short*)XZ +
                               ((size_t)(b * L_SEQ + ls)) * 384 + d0);
#pragma unroll
                for (int j = 0; j < 8; j++) {
                    float wk = (k == 0) ? w[j].x : (k == 1) ? w[j].y : (k == 2) ? w[j].z : w[j].w;
                    acc[j] += wk * us2f(xv[j]);
                }
            }
        }
        ushort8 ov;
#pragma unroll
        for (int j = 0; j < 8; j++) {
            bf16 tv = __float2bfloat16(silu_f(acc[j]));
            ov[j] = *(unsigned short*)&tv;
        }
        *(ushort8*)((unsigned short*)XS + (size_t)p * DI + d0) = ov;
        *(ushort8*)&xs_t[pl][d0] = ov;
    }
    __syncthreads();
    // ---- x_dbl GEMM: DBL[p0..p0+63][38 cols -> padded 40] ----
    int t = threadIdx.x;
    int w = t >> 6, lane = t & 63;
    int lm = lane & 15, quad = lane >> 4;
    const bf16* Wx = dirb ? bWxB : fWxB;
    float* DBL = dirb ? DBLB : DBLF;
    floatx4 acc[3];
#pragma unroll
    for (int tt = 0; tt < 3; tt++) acc[tt] = (floatx4){0.f, 0.f, 0.f, 0.f};
    const unsigned short* ar = &xs_t[w * 16 + lm][0];
#pragma unroll
    for (int k = 0; k < 6; k++) {
        int k0 = k * 32 + quad * 8;
        short8 a = *(const short8*)(ar + k0);
#pragma unroll
        for (int tt = 0; tt < 3; tt++) {
            int n = tt * 16 + lm;
            short8 bq = (n < 38) ? *(const short8*)((const short*)Wx + n * 192 + k0)
                                 : (short8){0,0,0,0,0,0,0,0};
            acc[tt] = __builtin_amdgcn_mfma_f32_16x16x32_bf16(a, bq, acc[tt], 0, 0, 0);
        }
    }
#pragma unroll
    for (int tt = 0; tt < 3; tt++) {
        int n = tt * 16 + lm;
        if (n < 38) {
            int nn = (n >= 6) ? n + 2 : n;
#pragma unroll
            for (int r = 0; r < 4; r++) {
                int m = p0 + w * 16 + quad * 4 + r;
                DBL[(size_t)m * LDBL + nn] = acc[tt][r];
            }
        }
    }
}

// ---------------------------------------------------------------------------
// Scan kernel A: per-group chunk scan + intra-group exclusive compose in LDS.
// Block = 16 chunks x 16 d (256 thr); grid = (12 dslices, 16 grps, 4 dirb).
// Exports: per-chunk exclusive (P,Q) f16 planes + group totals (Pg,Qg) f32.
// ---------------------------------------------------------------------------
__global__ void k_scan_p1g(const float* __restrict__ DBLF, const float* __restrict__ DBLB,
                           const bf16* __restrict__ XSF,  const bf16* __restrict__ XSB,
                           const float* __restrict__ fWdt, const float* __restrict__ fbdt,
                           const float* __restrict__ bWdt, const float* __restrict__ bbdt,
                           const float* __restrict__ a2tab,
                           f16* __restrict__ Pexc, f16* __restrict__ Qexc,
                           float* __restrict__ Pg, float* __restrict__ Qg) {
    __shared__ f16x8 Pl[2][GRP][16];   // [s8][chunk][dl]
    __shared__ f16x8 Ql[2][GRP][16];
    int dsl = blockIdx.x, grp = blockIdx.y, dirb = blockIdx.z;
    int t = threadIdx.x;
    int chunk = t >> 4, dl = t & 15;
    int d = dsl * 16 + dl;
    int b = dirb & 1, dir = dirb >> 1;
    int gc = grp * GRP + chunk;

    const float* DBL = dir ? DBLB : DBLF;
    const bf16*  XS  = dir ? XSB  : XSF;
    const float* wdt = (dir ? bWdt : fWdt) + d * 6;
    float bdtv = (dir ? bbdt : fbdt)[d];

    float wd[6];
#pragma unroll
    for (int r = 0; r < 6; r++) wd[r] = wdt[r];
    const float* a2p = a2tab + (dir * DI + d) * 16;
    float A2[16], h[16];
#pragma unroll
    for (int v = 0; v < 4; v++) {
        float4 a2v = *(const float4*)(a2p + 4 * v);
        A2[4*v] = a2v.x; A2[4*v+1] = a2v.y; A2[4*v+2] = a2v.z; A2[4*v+3] = a2v.w;
    }
#pragma unroll
    for (int s = 0; s < 16; s++) h[s] = 0.f;

    int l = dir ? (L_SEQ - 1 - gc * CHUNK) : gc * CHUNK;
    int stp = dir ? -1 : 1;
    float sumdel = 0.f;

    for (int i = 0; i < CHUNK; i++) {
        size_t p = (size_t)b * L_SEQ + l;
        const float* row = DBL + p * LDBL;
        float dtv = bdtv;
#pragma unroll
        for (int r = 0; r < 6; r++) dtv += row[r] * wd[r];
        float del = softplus_f(dtv);
        float xs  = b2f(XS[p * DI + d]);
        const float4* bm = (const float4*)(row + 8);
        float4 B0 = bm[0], B1 = bm[1], B2 = bm[2], B3 = bm[3];
        float Bm[16] = {B0.x,B0.y,B0.z,B0.w, B1.x,B1.y,B1.z,B1.w,
                        B2.x,B2.y,B2.z,B2.w, B3.x,B3.y,B3.z,B3.w};
        float dx = del * xs;
        sumdel += del;
#pragma unroll
        for (int s = 0; s < 16; s++) {
            float dA = exp2f(del * A2[s]);
            h[s] = dA * h[s] + dx * Bm[s];
        }
        l += stp;
    }
    {
        f16x8 p0, p1, q0, q1;
#pragma unroll
        for (int j = 0; j < 8; j++) {
            q0[j] = (f16)h[j];
            q1[j] = (f16)h[8 + j];
            p0[j] = (f16)exp2f(A2[j] * sumdel);
            p1[j] = (f16)exp2f(A2[8 + j] * sumdel);
        }
        Pl[0][chunk][dl] = p0; Pl[1][chunk][dl] = p1;
        Ql[0][chunk][dl] = q0; Ql[1][chunk][dl] = q1;
    }
    __syncthreads();

    // phase 2: exclusive scan over the GRP chunks, one (d,s) per thread
    {
        int s  = t & 15, dl2 = t >> 4;
        int s8 = s >> 3, sl = s & 7;
        f16* Pp = (f16*)&Pl[s8][0][dl2];   // chunk stride = 16 f16x8 = 128 f16
        f16* Qp = (f16*)&Ql[s8][0][dl2];
        float runP = 1.f, runQ = 0.f;
#pragma unroll
        for (int c = 0; c < GRP; c++) {
            float pv = (float)Pp[c * 128 + sl];
            float qv = (float)Qp[c * 128 + sl];
            Pp[c * 128 + sl] = (f16)runP;
            Qp[c * 128 + sl] = (f16)runQ;
            runQ = pv * runQ + qv;
            runP *= pv;
        }
        int d2 = dsl * 16 + dl2;
        size_t gidx = (((size_t)(dirb * NGRP + grp)) * DI + d2) * 16 + s;
        Pg[gidx] = runP;
        Qg[gidx] = runQ;
    }
    __syncthreads();

    // phase 3: export per-chunk exclusive (P,Q) to global s8-planes
    {
        size_t base = ((size_t)(dirb * NCH + gc) * DI + d) * 8;
        *(f16x8*)(Pexc + base)         = Pl[0][chunk][dl];
        *(f16x8*)(Pexc + PLANE + base) = Pl[1][chunk][dl];
        *(f16x8*)(Qexc + base)         = Ql[0][chunk][dl];
        *(f16x8*)(Qexc + PLANE + base) = Ql[1][chunk][dl];
    }
}

// ---------------------------------------------------------------------------
// Scan kernel B: replay with inline cross-group exclusive prefix (no p2b).
// ---------------------------------------------------------------------------
__global__ void k_scan_p3g(const float* __restrict__ DBLF, const float* __restrict__ DBLB,
                           const bf16* __restrict__ XSF,  const bf16* __restrict__ XSB,
                           const bf16* __restrict__ XZF,  const bf16* __restrict__ XZB,
                           const float* __restrict__ fWdt, const float* __restrict__ fbdt,
                           const float* __restrict__ bWdt, const float* __restrict__ bbdt,
                           const float* __restrict__ a2tab,
                           const float* __restrict__ fD,    const float* __restrict__ bD,
                           const f16* __restrict__ Pexc, const f16* __restrict__ Qexc,
                           const float* __restrict__ Pg, const float* __restrict__ Qg,
                           bf16* __restrict__ YSF, bf16* __restrict__ YSB) {
    __shared__ float qx[16][17];   // [dl][s] group-exclusive prefix
    int dsl = blockIdx.x, grp = blockIdx.y, dirb = blockIdx.z;
    int t = threadIdx.x;
    {
        int dl = t >> 4, s = t & 15;
        int d2 = dsl * 16 + dl;
        float runQ = 0.f;
        for (int g = 0; g < grp; g++) {
            size_t i = (((size_t)(dirb * NGRP + g)) * DI + d2) * 16 + s;
            runQ = Pg[i] * runQ + Qg[i];
        }
        qx[dl][s] = runQ;
    }
    __syncthreads();

    int chunk = t >> 4, dl = t & 15;
    int d = dsl * 16 + dl;
    int gc = grp * GRP + chunk;
    int b = dirb & 1, dir = dirb >> 1;

    const float* DBL = dir ? DBLB : DBLF;
    const bf16*  XS  = dir ? XSB  : XSF;
    const bf16*  XZ  = dir ? XZB  : XZF;
    const float* wdt = (dir ? bWdt : fWdt) + d * 6;
    float bdtv = (dir ? bbdt : fbdt)[d];
    float Dp = dir ? bD[d] : fD[d];
    bf16* Y = dir ? YSB : YSF;

    float wd[6];
#pragma unroll
    for (int r = 0; r < 6; r++) wd[r] = wdt[r];
    const float* a2p = a2tab + (dir * DI + d) * 16;
    float A2[16], h[16];
#pragma unroll
    for (int v = 0; v < 4; v++) {
        float4 a2v = *(const float4*)(a2p + 4 * v);
        A2[4*v] = a2v.x; A2[4*v+1] = a2v.y; A2[4*v+2] = a2v.z; A2[4*v+3] = a2v.w;
    }
    // h_start = Pexc * Qg_exclusive + Qexc
    {
        size_t base = ((size_t)(dirb * NCH + gc) * DI + d) * 8;
        f16x8 pe0 = *(const f16x8*)(Pexc + base);
        f16x8 pe1 = *(const f16x8*)(Pexc + PLANE + base);
        f16x8 qe0 = *(const f16x8*)(Qexc + base);
        f16x8 qe1 = *(const f16x8*)(Qexc + PLANE + base);
#pragma unroll
        for (int j = 0; j < 8; j++) {
            h[j]     = (float)pe0[j] * qx[dl][j]     + (float)qe0[j];
            h[8 + j] = (float)pe1[j] * qx[dl][8 + j] + (float)qe1[j];
        }
    }

    int l = dir ? (L_SEQ - 1 - gc * CHUNK) : gc * CHUNK;
    int stp = dir ? -1 : 1;

    for (int i = 0; i < CHUNK; i++) {
        size_t p = (size_t)b * L_SEQ + l;
        const float* row = DBL + p * LDBL;
        float dtv = bdtv;
#pragma unroll
        for (int r = 0; r < 6; r++) dtv += row[r] * wd[r];
        float del = softplus_f(dtv);
        float xs  = b2f(XS[p * DI + d]);
        float z   = b2f(XZ[p * 384 + 192 + d]);
        const float4* bm = (const float4*)(row + 8);
        float4 B0 = bm[0], B1 = bm[1], B2 = bm[2], B3 = bm[3];
        float4 C0 = bm[4], C1 = bm[5], C2 = bm[6], C3 = bm[7];
        float Bm[16] = {B0.x,B0.y,B0.z,B0.w, B1.x,B1.y,B1.z,B1.w,
                        B2.x,B2.y,B2.z,B2.w, B3.x,B3.y,B3.z,B3.w};
        float Cm[16] = {C0.x,C0.y,C0.z,C0.w, C1.x,C1.y,C1.z,C1.w,
                        C2.x,C2.y,C2.z,C2.w, C3.x,C3.y,C3.z,C3.w};
        float dx = del * xs;
        float pr = 0.f;
#pragma unroll
        for (int s = 0; s < 16; s++) {
            float dA = exp2f(del * A2[s]);
            h[s] = dA * h[s] + dx * Bm[s];
            pr += h[s] * Cm[s];
        }
        Y[p * DI + d] = __float2bfloat16((pr + xs * Dp) * silu_f(z));
        l += stp;
    }
}

// ---------------------------------------------------------------------------
// K6: out-projection (dual-A MFMA, YO in LDS) + residual + double LN
// + msff in-projection GEMM fused (XM2 tile stays in LDS; H written direct).
// ---------------------------------------------------------------------------
__global__ void k_out_mid(const bf16* __restrict__ Y1, const bf16* __restrict__ Y2,
                          const bf16* __restrict__ W,
                          const float* __restrict__ x, const float* __restrict__ gamma1,
                          const float* __restrict__ ln1w, const float* __restrict__ ln1b,
                          const bf16* __restrict__ mwinB,
                          float* __restrict__ XMID, bf16* __restrict__ H) {
    __shared__ float yt[DIM][TP + 1];
    __shared__ float xt[DIM][TP + 1];
    __shared__ float rs[8][TP], rss[8][TP];
    __shared__ float uu[TP], rr[TP];
    __shared__ __align__(16) unsigned short xmt[TP][104];
    int p0 = blockIdx.x * TP;
    int b = p0 >> 12, l0 = p0 & (L_SEQ - 1);
    int t = threadIdx.x;
    int tg = t >> 5, li = t & 31;

    // GEMM-1: YO tile = (Y1+Y2)[p0..p0+31] @ Wout^T -> yt[c][pos]
    {
        int w = t >> 6, lane = t & 63;
        int lm = lane & 15, quad = lane >> 4;
        int mh = w & 1, nb = (w >> 1) * 3;
        const short* A1p = (const short*)Y1 + (size_t)(p0 + mh * 16 + lm) * 192 + quad * 8;
        const short* A2p = (const short*)Y2 + (size_t)(p0 + mh * 16 + lm) * 192 + quad * 8;
        const short* Wp  = (const short*)W;
        floatx4 acc[3];
#pragma unroll
        for (int tt = 0; tt < 3; tt++) acc[tt] = (floatx4){0.f, 0.f, 0.f, 0.f};
#pragma unroll
        for (int k = 0; k < 6; k++) {
            int k0 = k * 32;
            short8 a1 = *(const short8*)(A1p + k0);
            short8 a2 = *(const short8*)(A2p + k0);
#pragma unroll
            for (int tt = 0; tt < 3; tt++) {
                int n = (nb + tt) * 16 + lm;
                short8 bq = *(const short8*)(Wp + (size_t)n * 192 + k0 + quad * 8);
                acc[tt] = __builtin_amdgcn_mfma_f32_16x16x32_bf16(a1, bq, acc[tt], 0, 0, 0);
                acc[tt] = __builtin_amdgcn_mfma_f32_16x16x32_bf16(a2, bq, acc[tt], 0, 0, 0);
            }
        }
#pragma unroll
        for (int tt = 0; tt < 3; tt++) {
            int c = (nb + tt) * 16 + lm;
#pragma unroll
            for (int r = 0; r < 4; r++)
                yt[c][mh * 16 + quad * 4 + r] = acc[tt][r];
        }
    }
    for (int idx = t; idx < DIM * TP; idx += 256) {
        int c = idx >> 5, q = idx & 31;
        xt[c][q] = x[((size_t)(b * DIM + c)) * L_SEQ + l0 + q];
    }
    __syncthreads();
    // stats of x (LN1)
    {
        float s = 0.f, ss = 0.f;
        for (int c = tg; c < DIM; c += 8) { float v = xt[c][li]; s += v; ss += v * v; }
        rs[tg][li] = s; rss[tg][li] = ss;
    }
    __syncthreads();
    if (t < TP) {
        float s = 0.f, ss = 0.f;
#pragma unroll
        for (int g = 0; g < 8; g++) { s += rs[g][t]; ss += rss[g][t]; }
        float u = s / DIM;
        uu[t] = u; rr[t] = rsqrtf(ss / DIM - u * u + 1e-6f);
    }
    __syncthreads();
    // v = x + gamma1*(yo + ln1(x)); stats of v
    {
        float u = uu[li], r = rr[li];
        float s = 0.f, ss = 0.f;
        for (int c = tg; c < DIM; c += 8) {
            float xv = xt[c][li];
            float x1 = ln1w[c] * (xv - u) * r + ln1b[c];
            float v = xv + gamma1[c] * (yt[c][li] + x1);
            XMID[((size_t)(b * DIM + c)) * L_SEQ + l0 + li] = v;
            xt[c][li] = v;
            s += v; ss += v * v;
        }
        rs[tg][li] = s; rss[tg][li] = ss;
    }
    __syncthreads();
    if (t < TP) {
        float s = 0.f, ss = 0.f;
#pragma unroll
        for (int g = 0; g < 8; g++) { s += rs[g][t]; ss += rss[g][t]; }
        float u = s / DIM;
        uu[t] = u; rr[t] = rsqrtf(ss / DIM - u * u + 1e-6f);
    }
    __syncthreads();
    // XM2 tile -> LDS (bf16, stride 104 shorts: 16B-aligned rows, 2-way bank = free)
    for (int idx = t; idx < DIM * TP; idx += 256) {
        int q = idx / DIM, c = idx % DIM;
        bf16 tv = __float2bfloat16(ln1w[c] * (xt[c][q] - uu[q]) * rr[q] + ln1b[c]);
        xmt[q][c] = *(unsigned short*)&tv;
    }
    __syncthreads();
    // GEMM-2: H[p0..p0+31][0..575] = XM2 @ mwin^T (K=96), acc reused per tile
    {
        int w = t >> 6, lane = t & 63;
        int lm = lane & 15, quad = lane >> 4;
        int mh = w & 1, ng = w >> 1;   // ng 0..1 -> n-tile halves
        const unsigned short* ar = &xmt[mh * 16 + lm][0];
        short8 a[3];
#pragma unroll
        for (int k = 0; k < 3; k++)
            a[k] = *(const short8*)(ar + k * 32 + quad * 8);
        const short* Wp = (const short*)mwinB;
#pragma unroll
        for (int tt = 0; tt < 18; tt++) {
            int n = (ng * 18 + tt) * 16 + lm;
            floatx4 acc = (floatx4){0.f, 0.f, 0.f, 0.f};
#pragma unroll
            for (int k = 0; k < 3; k++) {
                short8 bq = *(const short8*)(Wp + (size_t)n * 96 + k * 32 + quad * 8);
                acc = __builtin_amdgcn_mfma_f32_16x16x32_bf16(a[k], bq, acc, 0, 0, 0);
            }
#pragma unroll
            for (int r = 0; r < 4; r++) {
                int m = p0 + mh * 16 + quad * 4 + r;
                H[(size_t)m * 576 + n] = __float2bfloat16(acc[r]);
            }
        }
    }
}

// ---------------------------------------------------------------------------
// K7: fused dilated dwconvs + GELU gate (G in LDS) + msff out-projection
// + final residual (planar f32 out). Block = 32 positions.
// ---------------------------------------------------------------------------
__global__ void k_msff_outres(const bf16* __restrict__ H, const float* __restrict__ mdwt,
                              const bf16* __restrict__ mwoutB,
                              const float* __restrict__ XMID, const float* __restrict__ gamma2,
                              float* __restrict__ out) {
    __shared__ __align__(16) unsigned short gt[32][200];
    int p0 = blockIdx.x * 32;
    int t = threadIdx.x;
    const unsigned short* Hu = (const unsigned short*)H;

    for (int u = t; u < 32 * 24; u += 256) {
        int cg = u % 24, pl = u / 24;
        int p = p0 + pl;
        int c0 = cg * 8;
        int b = p >> 12, l = p & (L_SEQ - 1);
        int y = l >> 6, xc = l & 63;
        float a1[8] = {}, a2[8] = {}, a3[8] = {};
#pragma unroll
        for (int ky = 0; ky < 3; ky++) {
#pragma unroll
            for (int kx = 0; kx < 3; kx++) {
                int tap = ky * 3 + kx;
                {
                    int y1 = y + (ky - 1), x1 = xc + (kx - 1);
                    if (y1 >= 0 && y1 < 64 && x1 >= 0 && x1 < 64) {
                        float4 w0 = *(const float4*)(mdwt + tap * 192 + c0);
                        float4 w1 = *(const float4*)(mdwt + tap * 192 + c0 + 4);
                        ushort8 hv = *(const ushort8*)(Hu +
                            ((size_t)(b * L_SEQ + y1 * 64 + x1)) * 576 + c0);
                        float wv[8] = {w0.x,w0.y,w0.z,w0.w, w1.x,w1.y,w1.z,w1.w};
#pragma unroll
                        for (int j = 0; j < 8; j++) a1[j] += wv[j] * us2f(hv[j]);
                    }
                }
                {
                    int y2 = y + (ky - 1) * 2, x2 = xc + (kx - 1) * 2;
                    if (y2 >= 0 && y2 < 64 && x2 >= 0 && x2 < 64) {
                        float4 w0 = *(const float4*)(mdwt + (9 + tap) * 192 + c0);
                        float4 w1 = *(const float4*)(mdwt + (9 + tap) * 192 + c0 + 4);
                        ushort8 hv = *(const ushort8*)(Hu +
                            ((size_t)(b * L_SEQ + y2 * 64 + x2)) * 576 + 192 + c0);
                        float wv[8] = {w0.x,w0.y,w0.z,w0.w, w1.x,w1.y,w1.z,w1.w};
#pragma unroll
                        for (int j = 0; j < 8; j++) a2[j] += wv[j] * us2f(hv[j]);
                    }
                }
                {
                    int y3 = y + (ky - 1) * 3, x3 = xc + (kx - 1) * 3;
                    if (y3 >= 0 && y3 < 64 && x3 >= 0 && x3 < 64) {
                        float4 w0 = *(const float4*)(mdwt + (18 + tap) * 192 + c0);
                        float4 w1 = *(const float4*)(mdwt + (18 + tap) * 192 + c0 + 4);
                        ushort8 hv = *(const ushort8*)(Hu +
                            ((size_t)(b * L_SEQ + y3 * 64 + x3)) * 576 + 384 + c0);
                        float wv[8] = {w0.x,w0.y,w0.z,w0.w, w1.x,w1.y,w1.z,w1.w};
#pragma unroll
                        for (int j = 0; j < 8; j++) a3[j] += wv[j] * us2f(hv[j]);
                    }
                }
            }
        }
        ushort8 ov;
#pragma unroll
        for (int j = 0; j < 8; j++) {
            float ge = 0.5f * a1[j] * (1.f + erff(a1[j] * 0.70710678118f));
            bf16 tv = __float2bfloat16(ge * a2[j] * a3[j]);
            ov[j] = *(unsigned short*)&tv;
        }
        *(ushort8*)&gt[pl][c0] = ov;
    }
    __syncthreads();
    // GEMM: out = XMID + gamma2 * (mwout @ G^T)   (m = channel, n = position)
    int w = t >> 6, lane = t & 63;
    int lm = lane & 15, quad = lane >> 4;
    int nt = w & 1, mb = (w >> 1) * 3;
    floatx4 acc[3];
#pragma unroll
    for (int tt = 0; tt < 3; tt++) acc[tt] = (floatx4){0.f, 0.f, 0.f, 0.f};
    const unsigned short* br = &gt[nt * 16 + lm][0];
#pragma unroll
    for (int k = 0; k < 6; k++) {
        int k0 = k * 32 + quad * 8;
        short8 bq = *(const short8*)(br + k0);
#pragma unroll
        for (int tt = 0; tt < 3; tt++) {
            int m = (mb + tt) * 16 + lm;
            short8 a = *(const short8*)((const short*)mwoutB + m * 192 + k0);
            acc[tt] = __builtin_amdgcn_mfma_f32_16x16x32_bf16(a, bq, acc[tt], 0, 0, 0);
        }
    }
    int b = p0 >> 12, l0 = p0 & (L_SEQ - 1);
#pragma unroll
    for (int tt = 0; tt < 3; tt++) {
#pragma unroll
        for (int r = 0; r < 4; r++) {
            int m = (mb + tt) * 16 + quad * 4 + r;
            size_t idx = ((size_t)(b * DIM + m)) * L_SEQ + l0 + nt * 16 + lm;
            out[idx] = XMID[idx] + gamma2[m] * acc[tt][r];
        }
    }
}

// ---------------------------------------------------------------------------
extern "C" void kernel_launch(void* const* d_in, const int* in_sizes, int n_in,
                              void* d_out, int out_size, void* d_ws, size_t ws_size,
                              hipStream_t stream) {
    const float* x      = (const float*)d_in[0];
    const float* gamma1 = (const float*)d_in[1];
    const float* gamma2 = (const float*)d_in[2];
    const float* ln1w   = (const float*)d_in[3];
    const float* ln1b   = (const float*)d_in[4];
    const float* mnw    = (const float*)d_in[5];
    const float* mnb    = (const float*)d_in[6];
    const float* fWin   = (const float*)d_in[7];
    const float* fconvw = (const float*)d_in[8];
    const float* fconvb = (const float*)d_in[9];
    const float* fWx    = (const float*)d_in[10];
    const float* fWdt   = (const float*)d_in[11];
    const float* fbdt   = (const float*)d_in[12];
    const float* fAlog  = (const float*)d_in[13];
    const float* fD     = (const float*)d_in[14];
    const float* bWin   = (const float*)d_in[15];
    const float* bconvw = (const float*)d_in[16];
    const float* bconvb = (const float*)d_in[17];
    const float* bWx    = (const float*)d_in[18];
    const float* bWdt   = (const float*)d_in[19];
    const float* bbdt   = (const float*)d_in[20];
    const float* bAlog  = (const float*)d_in[21];
    const float* bD     = (const float*)d_in[22];
    const float* Wout   = (const float*)d_in[23];
    const float* mwin   = (const float*)d_in[24];
    const float* mdw1   = (const float*)d_in[25];
    const float* mdw2   = (const float*)d_in[26];
    const float* mdw3   = (const float*)d_in[27];
    const float* mwout  = (const float*)d_in[28];
    float* out = (float*)d_out;

    float* ws = (float*)d_ws;
    // float offsets
    bf16*  XNbf  = (bf16*)(ws);              // 786432 bf16
    bf16*  XZF   = (bf16*)(ws + 393216);     // 3145728 bf16
    bf16*  XZB   = (bf16*)(ws + 1966080);    // 3145728 bf16
    bf16*  XSF   = (bf16*)(ws + 3538944);    // 1572864 bf16
    bf16*  XSB   = (bf16*)(ws + 4325376);    // 1572864 bf16
    float* DBLF  = ws + 5111808;             // 327680
    float* DBLB  = ws + 5439488;             // 327680
    f16*   Ph    = (f16*)(ws + 5767168);     // Pexc: 2 planes x 1572864 f16
    f16*   Qh    = (f16*)(ws + 8912896);     // Qexc: 2 planes x 1572864 f16
    bf16*  YSFbf = (bf16*)(ws + 12058624);   // 1572864 bf16
    bf16*  YSBbf = (bf16*)(ws + 12845056);   // 1572864 bf16
    float* XMID  = ws + 14417920;            // 786432
    bf16*  Hcl   = (bf16*)(ws + 15597568);   // 4718592 bf16
    bf16*  WAR   = (bf16*)(ws + 18743296);   // 180480 bf16
    float* A2tab = ws + 18833536;            // 6144
    float* MDWT  = ws + 18839680;            // 5184
    float* Pgb   = ws + 18844864;            // 196608 (4*NGRP*DI*16)
    float* Qgb   = ws + 19041472;            // 196608

    const bf16* fWinB  = WAR;
    const bf16* bWinB  = WAR + 36864;
    const bf16* fWxB   = WAR + 73728;
    const bf16* bWxB   = WAR + 81024;
    const bf16* WoutB  = WAR + 88320;
    const bf16* mwinB  = WAR + 106752;
    const bf16* mwoutB = WAR + 162048;

    // 1. double LN (LDS-tiled) + prep as extra blocks
    k_ln12_prep<<<NPOS / TP + 750, 256, 0, stream>>>(
        x, ln1w, ln1b, mnw, mnb, XNbf,
        fWin, bWin, fWx, bWx, Wout, mwin, mwout,
        fAlog, bAlog, mdw1, mdw2, mdw3, WAR, A2tab, MDWT);
    // 2. in-projections, both dirs (clean bf16-weight MFMA)
    mfma_nt_dir<<<dim3(128, 6, 2), 256, 0, stream>>>(XNbf, XNbf, fWinB, bWinB,
                                                     XZF, XZB, NPOS, 384, DIM, 384, 0, 1);
    // 3. dwconv + silu + x_dbl projection (fused, both dirs)
    k_conv_dbl<<<dim3(NPOS / 64, 2), 256, 0, stream>>>(
        XZF, XZB, fconvw, fconvb, bconvw, bconvb,
        fWxB, bWxB, DBLF, DBLB, XSF, XSB);
    // 4-5. chunked parallel scan, CHUNK=16 (group compose in p1; prefix in p3)
    k_scan_p1g<<<dim3(DI / 16, NGRP, 4), 256, 0, stream>>>(
        DBLF, DBLB, XSF, XSB, fWdt, fbdt, bWdt, bbdt,
        A2tab, Ph, Qh, Pgb, Qgb);
    k_scan_p3g<<<dim3(DI / 16, NGRP, 4), 256, 0, stream>>>(
        DBLF, DBLB, XSF, XSB, XZF, XZB,
        fWdt, fbdt, bWdt, bbdt, A2tab, fD, bD,
        Ph, Qh, Pgb, Qgb, YSFbf, YSBbf);
    // 6. out-projection + residual + double LN + msff in-projection (fused)
    k_out_mid<<<NPOS / TP, 256, 0, stream>>>(
        YSFbf, YSBbf, WoutB, x, gamma1, ln1w, ln1b, mwinB, XMID, Hcl);
    // 7. msff dwconv/gate + out-projection + final residual (fused) -> out
    k_msff_outres<<<NPOS / 32, 256, 0, stream>>>(Hcl, MDWT, mwoutB, XMID, gamma2, out);
}